// Round 8
// baseline (338.691 us; speedup 1.0000x reference)
//
#include <hip/hip_runtime.h>
#include <hip/hip_fp16.h>

#define N_NODES 307
#define T_LEN   6000
#define L1      5991
#define L2      5982
#define ED      96
#define FDIM    95712
#define NCH2    16
#define LCPC    12                  // l-chunks per channel
#define CHL     499                 // rows per l-chunk (last = 493)
#define K5CH    (NCH2 * LCPC)       // 192 K-chunks, channel-pure

// ---- workspace layout (float offsets) ----
// consts: [0..7]=s1 [8..15]=t1 [16..31]=s2 [32..47]=t2
static const size_t WS_P1 = 256;                    // conv1 stat partials: 375*16
static const size_t WS_P2 = 8192;                   // conv2 stat partials: 3740*32
static const size_t WS_CS = 131072;                 // colsum partials: 192*96
static const size_t WS_NF = 155648;                 // node_feat 307*96
static const size_t WS_SP = 188416;                 // s_proj
static const size_t WS_RP = 221184;                 // r_proj
static const size_t WS_A2 = 262144;                 // a2: 95712*320
static const size_t WS_FP = 262144 + 30627840ull;   // fc partials: 192*96*320
// total = 36,788,224 floats ~= 147.2 MB

typedef _Float16 half8 __attribute__((ext_vector_type(8)));
typedef float f32x4 __attribute__((ext_vector_type(4)));

union U4H8 { uint4 u; half8 h; };

// pack fp32 -> (f16 hi | f16 lo<<16), x ~= hi + lo/2048
__device__ __forceinline__ unsigned int pack2h(float x) {
  __half h = __float2half(x);
  float r = (x - __half2float(h)) * 2048.0f;
  __half l = __float2half(r);
  return (unsigned int)__half_as_ushort(h) | ((unsigned int)__half_as_ushort(l) << 16);
}

// ================= K1: conv1 + relu, channel stats only =================
__global__ __launch_bounds__(320) void dgl_k1_conv1_stats(
    const float* __restrict__ nfeat, const float* __restrict__ w1,
    const float* __restrict__ b1, float* __restrict__ ws) {
  __shared__ float sw1[80], sb1[8];
  __shared__ float sred[5][16];
  int tid = threadIdx.x;
  if (tid < 80) sw1[tid] = w1[tid];
  if (tid < 8)  sb1[tid] = b1[tid];
  __syncthreads();
  int l0 = blockIdx.x * 16;
  int n = tid;
  bool nv = n < N_NODES;
  float xx[26];
#pragma unroll
  for (int j = 0; j < 26; ++j) {
    int t = l0 + j;
    xx[j] = (nv && t < T_LEN) ? nfeat[(size_t)t * N_NODES + n] : 0.f;
  }
  float s[8], q[8];
#pragma unroll
  for (int c = 0; c < 8; ++c) { s[c] = 0.f; q[c] = 0.f; }
#pragma unroll
  for (int dl = 0; dl < 16; ++dl) {
    int l = l0 + dl;
    if (nv && l < L1) {
#pragma unroll
      for (int c = 0; c < 8; ++c) {
        float r = sb1[c];
#pragma unroll
        for (int k = 0; k < 10; ++k) r = fmaf(xx[dl + k], sw1[c * 10 + k], r);
        float z = fmaxf(r, 0.f);
        s[c] += z; q[c] += z * z;
      }
    }
  }
  int wv = tid >> 6, ln = tid & 63;
#pragma unroll
  for (int c = 0; c < 8; ++c) {
    float vs = s[c], vq = q[c];
    for (int o = 32; o; o >>= 1) { vs += __shfl_down(vs, o, 64); vq += __shfl_down(vq, o, 64); }
    if (ln == 0) { sred[wv][c] = vs; sred[wv][8 + c] = vq; }
  }
  __syncthreads();
  if (tid < 16) {
    float t = 0.f;
    for (int w = 0; w < 5; ++w) t += sred[w][tid];
    ws[WS_P1 + (size_t)blockIdx.x * 16 + tid] = t;
  }
}

// ================= K2: finalize bn1 =================
__global__ void dgl_k2_fin1(const float* __restrict__ g1, const float* __restrict__ b1,
                            float* __restrict__ ws) {
  __shared__ double sd[16];
  int tid = threadIdx.x;
  if (tid < 16) {
    double a = 0.0;
    for (int j = 0; j < 375; ++j) a += (double)ws[WS_P1 + (size_t)j * 16 + tid];
    sd[tid] = a;
  }
  __syncthreads();
  if (tid < 8) {
    double cnt = (double)N_NODES * (double)L1;
    double m = sd[tid] / cnt;
    double v = sd[tid + 8] / cnt - m * m;
    double inv = 1.0 / sqrt(v + 1e-5);
    ws[tid]     = (float)((double)g1[tid] * inv);
    ws[8 + tid] = (float)((double)b1[tid] - (double)g1[tid] * inv * m);
  }
}

// ================= K3: fused conv1+bn1 (LDS window) -> conv2 (2 passes) + relu -> a2 + stats =================
__global__ __launch_bounds__(256, 4) void dgl_k3_conv2(
    const float* __restrict__ nfeat, const float* __restrict__ w1, const float* __restrict__ b1,
    const float* __restrict__ w2, const float* __restrict__ b2, float* __restrict__ ws) {
  __shared__ float sx[26][64];
  __shared__ float sz[4][17][64];
  __shared__ float sw2[1280], sw1[80], sb1[8], sb2[16], ss1[8], st1[8];
  __shared__ float wpart[4][8];
  int tid = threadIdx.x;
  int lane = tid & 63, g = tid >> 6;
  int l0 = blockIdx.x * 8, n0 = blockIdx.y * 64;
  for (int i = tid; i < 1280; i += 256) sw2[i] = w2[i];
  if (tid < 80) sw1[tid] = w1[tid];
  if (tid < 8)  { sb1[tid] = b1[tid]; ss1[tid] = ws[tid]; st1[tid] = ws[8 + tid]; }
  if (tid < 16) sb2[tid] = b2[tid];
  for (int i = tid; i < 26 * 64; i += 256) {
    int j = i >> 6, l2 = i & 63;
    int t = l0 + j, nn = n0 + l2;
    sx[j][l2] = (t < T_LEN && nn < N_NODES) ? nfeat[(size_t)t * N_NODES + nn] : 0.f;
  }
  float acc[4][8];
#pragma unroll
  for (int qq = 0; qq < 4; ++qq)
#pragma unroll
    for (int dl = 0; dl < 8; ++dl) acc[qq][dl] = 0.f;
  __syncthreads();
#pragma unroll 1
  for (int p = 0; p < 2; ++p) {
    {
      int c = p * 4 + g;
#pragma unroll
      for (int lz = 0; lz < 17; ++lz) {
        float r = sb1[c];
#pragma unroll
        for (int k = 0; k < 10; ++k) r = fmaf(sx[lz + k][lane], sw1[c * 10 + k], r);
        sz[g][lz][lane] = fmaf(ss1[c], fmaxf(r, 0.f), st1[c]);
      }
    }
    __syncthreads();
#pragma unroll
    for (int c4 = 0; c4 < 4; ++c4) {
      int cin = p * 4 + c4;
      float zr[17];
#pragma unroll
      for (int t = 0; t < 17; ++t) zr[t] = sz[c4][t][lane];
#pragma unroll
      for (int k = 0; k < 10; ++k) {
#pragma unroll
        for (int qq = 0; qq < 4; ++qq) {
          float w = sw2[(g * 4 + qq) * 80 + cin * 10 + k];
#pragma unroll
          for (int dl = 0; dl < 8; ++dl) acc[qq][dl] = fmaf(zr[dl + k], w, acc[qq][dl]);
        }
      }
    }
    __syncthreads();
  }
  int n = n0 + lane;
  bool nv = n < N_NODES;
  float s4[4] = {0.f, 0.f, 0.f, 0.f}, q4[4] = {0.f, 0.f, 0.f, 0.f};
#pragma unroll
  for (int qq = 0; qq < 4; ++qq) {
    int c2 = g * 4 + qq;
#pragma unroll
    for (int dl = 0; dl < 8; ++dl) {
      int l = l0 + dl;
      float v = 0.f;
      if (nv && l < L2) v = fmaxf(acc[qq][dl] + sb2[c2], 0.f);
      if (l < L2) ws[WS_A2 + ((size_t)c2 * L2 + l) * 320 + n] = v;
      s4[qq] += v; q4[qq] += v * v;
    }
  }
#pragma unroll
  for (int qq = 0; qq < 4; ++qq) {
    float vs = s4[qq], vq = q4[qq];
    for (int o = 32; o; o >>= 1) { vs += __shfl_down(vs, o, 64); vq += __shfl_down(vq, o, 64); }
    if (lane == 0) { wpart[g][qq] = vs; wpart[g][4 + qq] = vq; }
  }
  __syncthreads();
  if (tid < 32) {
    int c2 = tid & 15; bool isq = tid >= 16;
    float v = wpart[c2 >> 2][(isq ? 4 : 0) + (c2 & 3)];
    ws[WS_P2 + ((size_t)blockIdx.y * gridDim.x + blockIdx.x) * 32 + tid] = v;
  }
}

// ================= K4: finalize bn2 =================
__global__ __launch_bounds__(512) void dgl_k4_fin2(const float* __restrict__ g2,
                                                   const float* __restrict__ b2,
                                                   float* __restrict__ ws) {
  __shared__ double dd[32][17];
  int tid = threadIdx.x;
  int v = tid >> 4, p = tid & 15;
  double a = 0.0;
  for (int j = p; j < 3740; j += 16) a += (double)ws[WS_P2 + (size_t)j * 32 + v];
  dd[v][p] = a;
  __syncthreads();
  if (tid < 32) {
    double s = 0.0;
    for (int pp = 0; pp < 16; ++pp) s += dd[tid][pp];
    dd[tid][16] = s;
  }
  __syncthreads();
  if (tid < 16) {
    double cnt = (double)N_NODES * (double)L2;
    double m = dd[tid][16] / cnt;
    double var = dd[tid + 16][16] / cnt - m * m;
    double inv = 1.0 / sqrt(var + 1e-5);
    ws[16 + tid] = (float)((double)g2[tid] * inv);
    ws[32 + tid] = (float)((double)b2[tid] - (double)g2[tid] * inv * m);
  }
}

// ================= K4b: per-channel-chunk column sums of fc_w =================
__global__ __launch_bounds__(384) void dgl_k4b_colsum(const float* __restrict__ fcw,
                                                      float* __restrict__ ws) {
  __shared__ float red[4][96];
  int b = blockIdx.x;                 // 0..191
  int c = b / LCPC, lc = b % LCPC;
  int clen = (lc == LCPC - 1) ? (L2 - CHL * (LCPC - 1)) : CHL;
  size_t fb = (size_t)c * L2 + (size_t)lc * CHL;
  int tid = threadIdx.x, rg = tid / 96, e = tid % 96;
  float a = 0.f;
  for (int r = rg; r < clen; r += 4) a += fcw[(fb + r) * 96 + e];
  red[rg][e] = a;
  __syncthreads();
  if (tid < 96) {
    float t = red[0][tid] + red[1][tid] + red[2][tid] + red[3][tid];
    ws[WS_CS + (size_t)b * 96 + tid] = t;
  }
}

// ================= K5: split-K GEMM via f16x2-split MFMA (3 products) =================
// y = Ahi*Bhi + (Ahi*Blo + Alo*Bhi)/2048, dropped lo*lo ~ 2^-22 relative.
// Block: 256 thr (4 waves), tile 64n x 96e; wave w: n-sub [16w,16w+16), 6 e-tiles.
__global__ __launch_bounds__(256) void dgl_k5_fc(const float* __restrict__ fcw,
                                                 float* __restrict__ ws) {
  __shared__ unsigned int Ahl[64][44];   // pack(hi,lo) per element, [n][k] (k padded 32->44)
  __shared__ unsigned int Bhl[96][44];   // [e][k]
  int tid = threadIdx.x;
  int ch = blockIdx.x;
  int c = ch / LCPC, lc = ch % LCPC;
  int clen = (lc == LCPC - 1) ? (L2 - CHL * (LCPC - 1)) : CHL;
  size_t fb = (size_t)c * L2 + (size_t)lc * CHL;
  int n0 = blockIdx.y * 64;
  const float* a2 = ws + WS_A2;
  int wv = tid >> 6, lane = tid & 63;
  int m = lane & 15, g = lane >> 4;

  f32x4 acc1[6], acc2[6];
#pragma unroll
  for (int t = 0; t < 6; ++t) {
    acc1[t] = (f32x4){0.f, 0.f, 0.f, 0.f};
    acc2[t] = (f32x4){0.f, 0.f, 0.f, 0.f};
  }
  // staging indices
  int ka = tid >> 3, n8 = (tid & 7) * 8;            // A: row ka, cols n8..n8+7
  const float4 z4 = make_float4(0.f, 0.f, 0.f, 0.f);

#pragma unroll 1
  for (int ks = 0; ks < 16; ++ks) {
    int r0 = ks * 32;
    // ---- stage A (32k x 64n) ----
    {
      int rr = r0 + ka;
      bool ok = rr < clen;
      const float* src = a2 + (fb + rr) * 320 + n0 + n8;
      float4 va = ok ? *(const float4*)(src) : z4;
      float4 vb = ok ? *(const float4*)(src + 4) : z4;
      Ahl[n8 + 0][ka] = pack2h(va.x); Ahl[n8 + 1][ka] = pack2h(va.y);
      Ahl[n8 + 2][ka] = pack2h(va.z); Ahl[n8 + 3][ka] = pack2h(va.w);
      Ahl[n8 + 4][ka] = pack2h(vb.x); Ahl[n8 + 5][ka] = pack2h(vb.y);
      Ahl[n8 + 6][ka] = pack2h(vb.z); Ahl[n8 + 7][ka] = pack2h(vb.w);
    }
    // ---- stage B (32k x 96e) ----
#pragma unroll
    for (int i = 0; i < 3; ++i) {
      int fl = tid + i * 256;
      int kb = fl / 24, e4 = (fl % 24) * 4;
      int rr = r0 + kb;
      bool ok = rr < clen;
      float4 v = ok ? *(const float4*)(fcw + (fb + rr) * 96 + e4) : z4;
      Bhl[e4 + 0][kb] = pack2h(v.x); Bhl[e4 + 1][kb] = pack2h(v.y);
      Bhl[e4 + 2][kb] = pack2h(v.z); Bhl[e4 + 3][kb] = pack2h(v.w);
    }
    __syncthreads();
    // ---- A fragment (row m of wave's 16n, k = 8g..8g+7) ----
    uint4 a0 = *(const uint4*)&Ahl[16 * wv + m][8 * g];
    uint4 a1 = *(const uint4*)&Ahl[16 * wv + m][8 * g + 4];
    U4H8 Ahi, Alo;
    Ahi.u = make_uint4((a0.x & 0xFFFFu) | (a0.y << 16), (a0.z & 0xFFFFu) | (a0.w << 16),
                       (a1.x & 0xFFFFu) | (a1.y << 16), (a1.z & 0xFFFFu) | (a1.w << 16));
    Alo.u = make_uint4((a0.x >> 16) | (a0.y & 0xFFFF0000u), (a0.z >> 16) | (a0.w & 0xFFFF0000u),
                       (a1.x >> 16) | (a1.y & 0xFFFF0000u), (a1.z >> 16) | (a1.w & 0xFFFF0000u));
#pragma unroll
    for (int t = 0; t < 6; ++t) {
      uint4 b0 = *(const uint4*)&Bhl[16 * t + m][8 * g];
      uint4 b1 = *(const uint4*)&Bhl[16 * t + m][8 * g + 4];
      U4H8 Bhi, Blo;
      Bhi.u = make_uint4((b0.x & 0xFFFFu) | (b0.y << 16), (b0.z & 0xFFFFu) | (b0.w << 16),
                         (b1.x & 0xFFFFu) | (b1.y << 16), (b1.z & 0xFFFFu) | (b1.w << 16));
      Blo.u = make_uint4((b0.x >> 16) | (b0.y & 0xFFFF0000u), (b0.z >> 16) | (b0.w & 0xFFFF0000u),
                         (b1.x >> 16) | (b1.y & 0xFFFF0000u), (b1.z >> 16) | (b1.w & 0xFFFF0000u));
      acc1[t] = __builtin_amdgcn_mfma_f32_16x16x32_f16(Ahi.h, Bhi.h, acc1[t], 0, 0, 0);
      acc2[t] = __builtin_amdgcn_mfma_f32_16x16x32_f16(Ahi.h, Blo.h, acc2[t], 0, 0, 0);
      acc2[t] = __builtin_amdgcn_mfma_f32_16x16x32_f16(Alo.h, Bhi.h, acc2[t], 0, 0, 0);
    }
    __syncthreads();
  }
  // ---- epilogue: D col = lane&15 -> e, row = 4g + r -> n-local ----
  float* fp = ws + WS_FP;
#pragma unroll
  for (int t = 0; t < 6; ++t) {
    int e = 16 * t + m;
#pragma unroll
    for (int r = 0; r < 4; ++r) {
      int n = n0 + 16 * wv + 4 * g + r;
      fp[((size_t)ch * 96 + e) * 320 + n] = acc1[t][r] + acc2[t][r] * (1.0f / 2048.0f);
    }
  }
}

// ================= K6: fp64 combine (s2*P + t2*colsum + fcb) + relu + bn3 =================
__global__ __launch_bounds__(320) void dgl_k6_bn3(const float* __restrict__ fcb,
                                                  const float* __restrict__ g3,
                                                  const float* __restrict__ b3,
                                                  float* __restrict__ ws) {
  int e = blockIdx.x, tid = threadIdx.x;
  __shared__ double s2d[16], csd[16];
  __shared__ double rs[5], rq[5];
  __shared__ float mb[2];
  if (tid < 16) {
    s2d[tid] = (double)ws[16 + tid];
    double a = 0.0;
#pragma unroll
    for (int lc = 0; lc < LCPC; ++lc)
      a += (double)ws[WS_CS + (size_t)(tid * LCPC + lc) * 96 + e];
    csd[tid] = a * (double)ws[32 + tid];   // t2[c] * colsum_c[e]
  }
  __syncthreads();
  const float* fp = ws + WS_FP;
  double a = 0.0;
#pragma unroll 2
  for (int c = 0; c < 16; ++c) {
    double pc = 0.0;
    for (int lc = 0; lc < LCPC; ++lc) {
      int ch = c * LCPC + lc;
      pc += (double)fp[((size_t)ch * 96 + e) * 320 + tid];
    }
    a += s2d[c] * pc;
  }
  double cst = 0.0;
#pragma unroll
  for (int c = 0; c < 16; ++c) cst += csd[c];
  float x = fmaxf((float)(a + cst) + fcb[e], 0.f);
  if (tid >= N_NODES) x = 0.f;
  double s = (double)x, q = (double)x * (double)x;
  int wv = tid >> 6, ln = tid & 63;
  for (int o = 32; o; o >>= 1) { s += __shfl_down(s, o, 64); q += __shfl_down(q, o, 64); }
  if (ln == 0) { rs[wv] = s; rq[wv] = q; }
  __syncthreads();
  if (tid == 0) {
    double S = 0.0, Q = 0.0;
    for (int w = 0; w < 5; ++w) { S += rs[w]; Q += rq[w]; }
    double m = S / (double)N_NODES;
    double var = Q / (double)N_NODES - m * m;
    mb[0] = (float)m; mb[1] = (float)(1.0 / sqrt(var + 1e-5));
  }
  __syncthreads();
  if (tid < N_NODES)
    ws[WS_NF + (size_t)tid * 96 + e] = g3[e] * (x - mb[0]) * mb[1] + b3[e];
}

// ================= K7: s_proj / r_proj =================
__global__ __launch_bounds__(192) void dgl_k7_proj(const float* __restrict__ fow,
                                                   float* __restrict__ ws) {
  __shared__ float sh[96];
  int nI = blockIdx.x, tid = threadIdx.x;
  if (tid < 96) sh[tid] = ws[WS_NF + (size_t)nI * 96 + tid];
  __syncthreads();
  int col = tid % 96, half = tid / 96;
  float a = 0.f;
#pragma unroll 8
  for (int d = 0; d < 96; ++d) a = fmaf(sh[d], fow[(size_t)(half * 96 + d) * 96 + col], a);
  ws[(half ? WS_RP : WS_SP) + (size_t)nI * 96 + col] = a;
}

// ================= K8: edge relu + logits + gumbel + hard argmax -> adj =================
__global__ __launch_bounds__(256) void dgl_k8_edge(const float* __restrict__ fob,
                                                   const float* __restrict__ fcatw,
                                                   const float* __restrict__ fcatb,
                                                   const float* __restrict__ unif,
                                                   const float* __restrict__ ws,
                                                   float* __restrict__ out) {
  __shared__ float rp[16][100], sp[16][100], bb[96], wa[96], wb[96];
  int tid = threadIdx.x;
  int i0 = blockIdx.y * 16, j0 = blockIdx.x * 16;
  for (int idx = tid; idx < 16 * 96; idx += 256) {
    int r = idx / 96, e = idx % 96;
    int ii = i0 + r, jj = j0 + r;
    rp[r][e] = (ii < N_NODES) ? ws[WS_RP + (size_t)ii * 96 + e] : 0.f;
    sp[r][e] = (jj < N_NODES) ? ws[WS_SP + (size_t)jj * 96 + e] : 0.f;
  }
  if (tid < 96) { bb[tid] = fob[tid]; wa[tid] = fcatw[2 * tid]; wb[tid] = fcatw[2 * tid + 1]; }
  __syncthreads();
  int il = tid >> 4, jl = tid & 15;
  int i = i0 + il, j = j0 + jl;
  float a0 = 0.f, a1 = 0.f;
#pragma unroll 4
  for (int e = 0; e < 96; ++e) {
    float ef = fmaxf(rp[il][e] + sp[jl][e] + bb[e], 0.f);
    a0 = fmaf(ef, wa[e], a0);
    a1 = fmaf(ef, wb[e], a1);
  }
  if (i < N_NODES && j < N_NODES) {
    size_t ue = ((size_t)i * N_NODES + j) * 2;
    float g0 = -logf(-logf(unif[ue] + 1e-20f) + 1e-20f);
    float g1 = -logf(-logf(unif[ue + 1] + 1e-20f) + 1e-20f);
    float z0 = a0 + fcatb[0] + g0;
    float z1 = a1 + fcatb[1] + g1;
    out[(size_t)i * N_NODES + j] = (i == j) ? 0.f : ((z0 >= z1) ? 1.f : 0.f);
  }
}

extern "C" void kernel_launch(void* const* d_in, const int* in_sizes, int n_in,
                              void* d_out, int out_size, void* d_ws, size_t ws_size,
                              hipStream_t stream) {
  const float* nfeat = (const float*)d_in[1];
  const float* w1    = (const float*)d_in[2];
  const float* b1    = (const float*)d_in[3];
  const float* w2    = (const float*)d_in[4];
  const float* b2    = (const float*)d_in[5];
  const float* g1    = (const float*)d_in[6];
  const float* bb1   = (const float*)d_in[7];
  const float* g2    = (const float*)d_in[8];
  const float* bb2   = (const float*)d_in[9];
  const float* g3    = (const float*)d_in[10];
  const float* bb3   = (const float*)d_in[11];
  const float* fcw   = (const float*)d_in[12];
  const float* fcb   = (const float*)d_in[13];
  const float* fow   = (const float*)d_in[14];
  const float* fob   = (const float*)d_in[15];
  const float* fcatw = (const float*)d_in[16];
  const float* fcatb = (const float*)d_in[17];
  const float* unif  = (const float*)d_in[18];
  float* ws  = (float*)d_ws;
  float* out = (float*)d_out;

  dgl_k4b_colsum<<<dim3(K5CH), dim3(384), 0, stream>>>(fcw, ws);
  dgl_k1_conv1_stats<<<dim3(375), dim3(320), 0, stream>>>(nfeat, w1, b1, ws);
  dgl_k2_fin1<<<dim3(1), dim3(64), 0, stream>>>(g1, bb1, ws);
  dgl_k3_conv2<<<dim3(748, 5), dim3(256), 0, stream>>>(nfeat, w1, b1, w2, b2, ws);
  dgl_k4_fin2<<<dim3(1), dim3(512), 0, stream>>>(g2, bb2, ws);
  dgl_k5_fc<<<dim3(K5CH, 5), dim3(256), 0, stream>>>(fcw, ws);
  dgl_k6_bn3<<<dim3(96), dim3(320), 0, stream>>>(fcb, g3, bb3, ws);
  dgl_k7_proj<<<dim3(307), dim3(192), 0, stream>>>(fow, ws);
  dgl_k8_edge<<<dim3(20, 20), dim3(256), 0, stream>>>(fob, fcatw, fcatb, unif, ws, out);
}